// Round 9
// baseline (340.491 us; speedup 1.0000x reference)
//
#include <hip/hip_runtime.h>

// image (1,1024,1024) f32, x (16,1,1024,1024) f32, W_KL (9,1,3,3) f32, b_KL (9,) f32.
// y[b,h,w] = sum_{a,d} (conv(image,W_KL)[a*3+d][h,w] + b[a*3+d]) * x[b,h+a-1,w+d-1]
#define IH 1024
#define IW 1024
#define NB 16
#define NB2 8   // batches per block (z-split: 2 groups of 8)

typedef float v4f __attribute__((ext_vector_type(4)));

#define VMWAIT(n) asm volatile("s_waitcnt vmcnt(" #n ")" ::: "memory")
#define SCHEDB()  __builtin_amdgcn_sched_barrier(0)

__device__ __forceinline__ void glds16(const float* g, float* l) {
    __builtin_amdgcn_global_load_lds(
        (const __attribute__((address_space(1))) void*)g,
        (__attribute__((address_space(3))) void*)l, 16, 0, 0);
}

// Image window in registers: aligned v4f core + scalar halo dwords, rows
// clamped in-bounds; zero-padding applied in fin_win_img.
struct RawWin { v4f mv[3]; float fl[3]; float fr[3]; };

__device__ __forceinline__ void issue_win(const float* __restrict__ plane,
                                          int h, int w0, RawWin& rw) {
#pragma unroll
    for (int a = 0; a < 3; ++a) {
        const int hh = h + a - 1;
        const int hc = (hh < 0) ? 0 : (hh >= IH ? IH - 1 : hh);
        const float* rowp = plane + (size_t)hc * IW;
        rw.fl[a] = rowp[w0 > 0 ? w0 - 1 : 0];
        rw.mv[a] = *(const v4f*)(rowp + w0);
        rw.fr[a] = rowp[w0 + 4 < IW ? w0 + 4 : IW - 1];
    }
}

__device__ __forceinline__ void fin_win_img(const RawWin& rw, int h, int w0,
                                            float win[3][6]) {
#pragma unroll
    for (int a = 0; a < 3; ++a) {
        const int hh = h + a - 1;
        const bool rowok = (hh >= 0) & (hh < IH);
        win[a][0] = (rowok && w0 > 0)      ? rw.fl[a]   : 0.f;
        win[a][1] = rowok ? rw.mv[a].x : 0.f;
        win[a][2] = rowok ? rw.mv[a].y : 0.f;
        win[a][3] = rowok ? rw.mv[a].z : 0.f;
        win[a][4] = rowok ? rw.mv[a].w : 0.f;
        win[a][5] = (rowok && w0 + 4 < IW) ? rw.fr[a]   : 0.f;
    }
}

// Round-7 structure with ONE change: NO stores inside the batch loop.
// r4-r8 analysis: the per-iter queue was [store(b-1), stage xG, halo x6] and
// vmcnt retirement is IN-ORDER, so VMWAIT(6) forced the nontemporal store
// (HBM-deep ack, ~600-900cy) to fully retire EVERY iteration, phase-locked
// across all resident waves at the barrier -> why occupancy/depth levers
// were all null. Here outputs accumulate in registers (yacc[8], 32 VGPR,
// static indexing) and all 8 nt stores issue fire-and-forget AFTER the last
// consume (kernel-end drain covers them). Loop queue is pure [stage G,
// halo 6]; VMWAIT(6) retires exactly the stage loads.
__global__ __launch_bounds__(256, 4) void fused_regout(
    const float* __restrict__ image,
    const float* __restrict__ x,
    const float* __restrict__ Wk,
    const float* __restrict__ bk,
    float* __restrict__ out)
{
    __shared__ float lds[2][6][256];          // 12 KiB, double-buffered

    const int tx = threadIdx.x;               // lane 0..63
    const int wv = threadIdx.y;               // wave 0..3 = row within group

    // XCD-band swizzle, z in the chunk LSB so the (bz=0,bz=1) pair sharing
    // rows lands on the SAME XCD (keeps x-rows single-fetch per L2).
    const int hwid  = blockIdx.x;             // 0..2047
    const int xcd   = hwid & 7;
    const int chunk = hwid >> 3;              // 0..255
    const int bz    = chunk & 1;              // batch-group 0/1
    const int bx    = (chunk >> 1) & 3;       // col-tile 0..3
    const int g     = xcd * 32 + (chunk >> 3);// row-group 0..255 (bijective)
    const int c0    = bx * 256;
    const int h0    = g * 4;
    const int h     = h0 + wv;
    const int lc    = tx * 4;                 // local col of first out px
    const int w0    = c0 + lc;                // global col
    const int b0    = bz * NB2;               // first batch of this block

    const size_t plane = (size_t)IH * IW;

    // Opaque zero in a VGPR: forces halo broadcast loads to stay VMEM
    // (scalarization to SMEM would silently break the vmcnt group counts).
    int zv; asm("v_mov_b32 %0, 0" : "=v"(zv));

    // stage batch gb's 6-row tile into lds[buf]: wave wv does row wv
    // (+ row wv+4 for wv<2): G = 2,2,1,1 glds per wave.
    auto stage = [&](int gb, int buf) {
        const float* xb = x + (size_t)gb * plane;
        int gr = h0 - 1 + wv; gr = gr < 0 ? 0 : gr;               // rows -1..2 clamp lo
        glds16(xb + (size_t)gr * IW + c0 + tx * 4, &lds[buf][wv][0]);
        if (wv < 2) {
            int g2 = h0 + 3 + wv; g2 = g2 > IH - 1 ? IH - 1 : g2; // rows 3..4 clamp hi
            glds16(xb + (size_t)g2 * IW + c0 + tx * 4, &lds[buf][wv + 4][0]);
        }
    };
    // column-halo for batch gb: cols c0-1 / c0+256 for this thread's 3 rows,
    // broadcast loads (all lanes same address), 6 VMEM ops per wave.
    auto halo = [&](int gb, float* HL, float* HR) {
        const float* xb = x + (size_t)gb * plane;
        const int cl = (c0 > 0) ? c0 - 1 : 0;
        const int cr = (c0 + 256 < IW) ? c0 + 256 : IW - 1;
#pragma unroll
        for (int a = 0; a < 3; ++a) {
            int gr = h + a - 1; gr = gr < 0 ? 0 : (gr > IH - 1 ? IH - 1 : gr);
            const float* rp = xb + (size_t)gr * IW;
            HL[a] = rp[cl + zv];
            HR[a] = rp[cr + zv];
        }
    };

    // ---- prologue issue order (vmcnt groups, oldest first):
    // [image x9][stage(b0) xG][halo(b0) x6][stage(b0+1) xG][halo(b0+1) x6]
    RawWin rimg;
    issue_win(image, h, w0, rimg);
    SCHEDB();
    float hl[2][3], hr[2][3];
    stage(b0, 0);                 SCHEDB();
    halo(b0, hl[0], hr[0]);       SCHEDB();
    stage(b0 + 1, 1);             SCHEDB();
    halo(b0 + 1, hl[1], hr[1]);   SCHEDB();

    // conv weights / bias: uniform addresses -> scalar loads (lgkmcnt, does
    // not perturb the vmcnt counting).
    float wkk[81];
#pragma unroll
    for (int i = 0; i < 81; ++i) wkk[i] = Wk[i];
    float bb[9];
#pragma unroll
    for (int c = 0; c < 9; ++c) bb[c] = bk[c];

    // ---- K phase (auto-wait retires image loads; stages keep flying) ----
    float p[3][6];
    fin_win_img(rimg, h, w0, p);
    float Kv[4][9];
#pragma unroll
    for (int j = 0; j < 4; ++j)
#pragma unroll
        for (int c = 0; c < 9; ++c) {
            float acc = bb[c];
#pragma unroll
            for (int a = 0; a < 3; ++a)
#pragma unroll
                for (int d = 0; d < 3; ++d)
                    acc = fmaf(wkk[c * 9 + a * 3 + d], p[a][j + d], acc);
            Kv[j][c] = acc;
        }
    // Row-pad masking folded into Kv (staged clamp-row garbage then adds 0).
    {
        const bool top = (h == 0);
        const bool bot = (h == IH - 1);
#pragma unroll
        for (int j = 0; j < 4; ++j)
#pragma unroll
            for (int d = 0; d < 3; ++d) {
                Kv[j][d]     = top ? 0.f : Kv[j][d];
                Kv[j][6 + d] = bot ? 0.f : Kv[j][6 + d];
            }
    }

    // prologue sync: retire stage(b0); keep halo(b0)+stage(b1)+halo(b1)
    // in flight: younger = 6 + G + 6 = 12+G -> vmcnt(14/13).
    if (wv < 2) { VMWAIT(14); } else { VMWAIT(13); }
    SCHEDB();
    __builtin_amdgcn_s_barrier();
    SCHEDB();

    v4f yacc[NB2];                            // per-batch outputs, 32 VGPRs
    const int ll = (tx > 0)  ? lc - 4 : 0;    // aligned left-halo b128
    const int lr = (tx < 63) ? lc + 4 : 252;  // aligned right-halo b128

#pragma unroll
    for (int b = 0; b < NB2; ++b) {
        const int gb = b0 + b;
        // per-iter VMEM group: [stage(b+1) x G, halo(b+1) x 6] — NO store.
        if (b + 1 < NB2) {
            stage(gb + 1, (b + 1) & 1);                      SCHEDB();
            halo(gb + 1, hl[(b + 1) & 1], hr[(b + 1) & 1]);  SCHEDB();
        }
        // ---- consume batch b from lds[b&1] (halo(b) regs auto-waited,
        //      their wait leaves stage/halo(b+1) in flight) ----
        {
            const float* lb = &lds[b & 1][0][0];
            float win[3][6];
#pragma unroll
            for (int a = 0; a < 3; ++a) {
                const float* rowp = lb + (wv + a) * 256;
                const v4f lv = *(const v4f*)(rowp + ll);
                const v4f mv = *(const v4f*)(rowp + lc);
                const v4f rv = *(const v4f*)(rowp + lr);
                const float le = (tx == 0)  ? hl[b & 1][a] : lv.w;
                const float re = (tx == 63) ? hr[b & 1][a] : rv.x;
                win[a][0] = (w0 > 0)      ? le : 0.f;
                win[a][1] = mv.x; win[a][2] = mv.y;
                win[a][3] = mv.z; win[a][4] = mv.w;
                win[a][5] = (w0 + 4 < IW) ? re : 0.f;
            }
            v4f yy;
#pragma unroll
            for (int j = 0; j < 4; ++j) {
                float acc = 0.f;
#pragma unroll
                for (int a = 0; a < 3; ++a)
#pragma unroll
                    for (int d = 0; d < 3; ++d)
                        acc = fmaf(Kv[j][a * 3 + d], win[a][j + d], acc);
                yy[j] = acc;
            }
            yacc[b] = yy;
        }
        if (b + 1 < NB2) {
            // counted drain: retire stage(b+1) (LDS write landed); keep
            // halo(b+1) x 6 in flight. Then raw barrier (no vmcnt(0) drain).
            VMWAIT(6);
            SCHEDB();
            __builtin_amdgcn_s_barrier();
            SCHEDB();
        }
    }

    // ---- epilogue: fire-and-forget store burst (kernel-end drain) ----
    float* obp = out + (size_t)h * IW + w0;
#pragma unroll
    for (int b = 0; b < NB2; ++b)
        __builtin_nontemporal_store(yacc[b],
                                    (v4f*)(obp + (size_t)(b0 + b) * plane));
}

extern "C" void kernel_launch(void* const* d_in, const int* in_sizes, int n_in,
                              void* d_out, int out_size, void* d_ws, size_t ws_size,
                              hipStream_t stream) {
    const float* image = (const float*)d_in[0]; // 1*1024*1024
    const float* x     = (const float*)d_in[1]; // 16*1*1024*1024
    const float* Wk    = (const float*)d_in[2]; // 9*1*3*3
    const float* bk    = (const float*)d_in[3]; // 9
    float* out = (float*)d_out;                 // 16*1024*1024 f32

    dim3 block(64, 4);
    dim3 grid(2048);                            // 2 batch-groups x 1024 tiles
    fused_regout<<<grid, block, 0, stream>>>(image, x, Wk, bk, out);
}

// Round 10
// 207.346 us; speedup vs baseline: 1.6421x; 1.6421x over previous
//
#include <hip/hip_runtime.h>

// image (1,1024,1024) f32, x (16,1,1024,1024) f32, W_KL (9,1,3,3) f32, b_KL (9,) f32.
// y[b,h,w] = sum_{a,d} (conv(image,W_KL)[a*3+d][h,w] + b[a*3+d]) * x[b,h+a-1,w+d-1]
#define IH 1024
#define IW 1024
#define NB 16
#define NB2 4   // batches per block (z-split: 4 groups of 4)

typedef float v4f __attribute__((ext_vector_type(4)));

#define VMWAIT(n) asm volatile("s_waitcnt vmcnt(" #n ")" ::: "memory")
#define SCHEDB()  __builtin_amdgcn_sched_barrier(0)

__device__ __forceinline__ void glds16(const float* g, float* l) {
    __builtin_amdgcn_global_load_lds(
        (const __attribute__((address_space(1))) void*)g,
        (__attribute__((address_space(3))) void*)l, 16, 0, 0);
}

// Image window in registers: aligned v4f core + scalar halo dwords, rows
// clamped in-bounds; zero-padding applied in fin_win_img.
struct RawWin { v4f mv[3]; float fl[3]; float fr[3]; };

__device__ __forceinline__ void issue_win(const float* __restrict__ plane,
                                          int h, int w0, RawWin& rw) {
#pragma unroll
    for (int a = 0; a < 3; ++a) {
        const int hh = h + a - 1;
        const int hc = (hh < 0) ? 0 : (hh >= IH ? IH - 1 : hh);
        const float* rowp = plane + (size_t)hc * IW;
        rw.fl[a] = rowp[w0 > 0 ? w0 - 1 : 0];
        rw.mv[a] = *(const v4f*)(rowp + w0);
        rw.fr[a] = rowp[w0 + 4 < IW ? w0 + 4 : IW - 1];
    }
}

__device__ __forceinline__ void fin_win_img(const RawWin& rw, int h, int w0,
                                            float win[3][6]) {
#pragma unroll
    for (int a = 0; a < 3; ++a) {
        const int hh = h + a - 1;
        const bool rowok = (hh >= 0) & (hh < IH);
        win[a][0] = (rowok && w0 > 0)      ? rw.fl[a]   : 0.f;
        win[a][1] = rowok ? rw.mv[a].x : 0.f;
        win[a][2] = rowok ? rw.mv[a].y : 0.f;
        win[a][3] = rowok ? rw.mv[a].z : 0.f;
        win[a][4] = rowok ? rw.mv[a].w : 0.f;
        win[a][5] = (rowok && w0 + 4 < IW) ? rw.fr[a]   : 0.f;
    }
}

// Round-7 structure + store-removal, SIZED TO AVOID THE SPILL CLIFF.
// r9 lesson: with yacc[8] (peak live ~110) the allocator pinned VGPR=64 and
// spilled ~1KB/thread to scratch (WRITE 611MB, 260us) instead of using the
// 128 cap. Here NB2=4 -> yacc[4]=16 VGPRs, peak live ~80: fits the
// allocator's 64-96 comfort zone. Loop VMEM queue is PURE LOADS
// [stage xG, halo x6] -- in-order vmcnt retirement never forces a store
// ack (r4-r8: store(b-1) sat oldest in every waited prefix, serializing
// ~600-900cy of HBM store ack per batch, phase-locked at the barrier).
// The 4 nt stores issue fire-and-forget at kernel end.
__global__ __launch_bounds__(256, 4) void fused_ro4(
    const float* __restrict__ image,
    const float* __restrict__ x,
    const float* __restrict__ Wk,
    const float* __restrict__ bk,
    float* __restrict__ out)
{
    __shared__ float lds[2][6][256];          // 12 KiB, double-buffered

    const int tx = threadIdx.x;               // lane 0..63
    const int wv = threadIdx.y;               // wave 0..3 = row within group

    // XCD-band swizzle; z (2 bits) in the chunk LSBs so all 4 batch-groups
    // sharing the same rows land on the SAME XCD (single-fetch per L2).
    const int hwid  = blockIdx.x;             // 0..4095
    const int xcd   = hwid & 7;
    const int chunk = hwid >> 3;              // 0..511
    const int bz    = chunk & 3;              // batch-group 0..3
    const int bx    = (chunk >> 2) & 3;       // col-tile 0..3
    const int g     = xcd * 32 + (chunk >> 4);// row-group 0..255 (bijective)
    const int c0    = bx * 256;
    const int h0    = g * 4;
    const int h     = h0 + wv;
    const int lc    = tx * 4;                 // local col of first out px
    const int w0    = c0 + lc;                // global col
    const int b0    = bz * NB2;               // first batch of this block

    const size_t plane = (size_t)IH * IW;

    // Opaque zero in a VGPR: forces halo broadcast loads to stay VMEM
    // (scalarization to SMEM would silently break the vmcnt group counts).
    int zv; asm("v_mov_b32 %0, 0" : "=v"(zv));

    // stage batch gb's 6-row tile into lds[buf]: wave wv does row wv
    // (+ row wv+4 for wv<2): G = 2,2,1,1 glds per wave.
    auto stage = [&](int gb, int buf) {
        const float* xb = x + (size_t)gb * plane;
        int gr = h0 - 1 + wv; gr = gr < 0 ? 0 : gr;               // rows -1..2 clamp lo
        glds16(xb + (size_t)gr * IW + c0 + tx * 4, &lds[buf][wv][0]);
        if (wv < 2) {
            int g2 = h0 + 3 + wv; g2 = g2 > IH - 1 ? IH - 1 : g2; // rows 3..4 clamp hi
            glds16(xb + (size_t)g2 * IW + c0 + tx * 4, &lds[buf][wv + 4][0]);
        }
    };
    // column-halo for batch gb: cols c0-1 / c0+256 for this thread's 3 rows,
    // broadcast loads (all lanes same address), 6 VMEM ops per wave.
    auto halo = [&](int gb, float* HL, float* HR) {
        const float* xb = x + (size_t)gb * plane;
        const int cl = (c0 > 0) ? c0 - 1 : 0;
        const int cr = (c0 + 256 < IW) ? c0 + 256 : IW - 1;
#pragma unroll
        for (int a = 0; a < 3; ++a) {
            int gr = h + a - 1; gr = gr < 0 ? 0 : (gr > IH - 1 ? IH - 1 : gr);
            const float* rp = xb + (size_t)gr * IW;
            HL[a] = rp[cl + zv];
            HR[a] = rp[cr + zv];
        }
    };

    // ---- prologue issue order (vmcnt groups, oldest first):
    // [image x9][stage(b0) xG][halo(b0) x6][stage(b0+1) xG][halo(b0+1) x6]
    RawWin rimg;
    issue_win(image, h, w0, rimg);
    SCHEDB();
    float hl[2][3], hr[2][3];
    stage(b0, 0);                 SCHEDB();
    halo(b0, hl[0], hr[0]);       SCHEDB();
    stage(b0 + 1, 1);             SCHEDB();
    halo(b0 + 1, hl[1], hr[1]);   SCHEDB();

    // conv weights / bias: uniform addresses -> scalar loads (lgkmcnt, does
    // not perturb the vmcnt counting).
    float wkk[81];
#pragma unroll
    for (int i = 0; i < 81; ++i) wkk[i] = Wk[i];
    float bb[9];
#pragma unroll
    for (int c = 0; c < 9; ++c) bb[c] = bk[c];

    // ---- K phase (auto-wait retires image loads; stages keep flying) ----
    float p[3][6];
    fin_win_img(rimg, h, w0, p);
    float Kv[4][9];
#pragma unroll
    for (int j = 0; j < 4; ++j)
#pragma unroll
        for (int c = 0; c < 9; ++c) {
            float acc = bb[c];
#pragma unroll
            for (int a = 0; a < 3; ++a)
#pragma unroll
                for (int d = 0; d < 3; ++d)
                    acc = fmaf(wkk[c * 9 + a * 3 + d], p[a][j + d], acc);
            Kv[j][c] = acc;
        }
    // Row-pad masking folded into Kv (staged clamp-row garbage then adds 0).
    {
        const bool top = (h == 0);
        const bool bot = (h == IH - 1);
#pragma unroll
        for (int j = 0; j < 4; ++j)
#pragma unroll
            for (int d = 0; d < 3; ++d) {
                Kv[j][d]     = top ? 0.f : Kv[j][d];
                Kv[j][6 + d] = bot ? 0.f : Kv[j][6 + d];
            }
    }

    // prologue sync: retire stage(b0); keep halo(b0)+stage(b1)+halo(b1)
    // in flight: younger = 6 + G + 6 = 12+G -> vmcnt(14/13).
    if (wv < 2) { VMWAIT(14); } else { VMWAIT(13); }
    SCHEDB();
    __builtin_amdgcn_s_barrier();
    SCHEDB();

    v4f yacc[NB2];                            // per-batch outputs, 16 VGPRs
    const int ll = (tx > 0)  ? lc - 4 : 0;    // aligned left-halo b128
    const int lr = (tx < 63) ? lc + 4 : 252;  // aligned right-halo b128

#pragma unroll
    for (int b = 0; b < NB2; ++b) {
        const int gb = b0 + b;
        // per-iter VMEM group: [stage(b+1) x G, halo(b+1) x 6] — NO store.
        if (b + 1 < NB2) {
            stage(gb + 1, (b + 1) & 1);                      SCHEDB();
            halo(gb + 1, hl[(b + 1) & 1], hr[(b + 1) & 1]);  SCHEDB();
        }
        // ---- consume batch b from lds[b&1] (halo(b) regs auto-waited;
        //      that wait leaves stage/halo(b+1) in flight) ----
        {
            const float* lb = &lds[b & 1][0][0];
            float win[3][6];
#pragma unroll
            for (int a = 0; a < 3; ++a) {
                const float* rowp = lb + (wv + a) * 256;
                const v4f lv = *(const v4f*)(rowp + ll);
                const v4f mv = *(const v4f*)(rowp + lc);
                const v4f rv = *(const v4f*)(rowp + lr);
                const float le = (tx == 0)  ? hl[b & 1][a] : lv.w;
                const float re = (tx == 63) ? hr[b & 1][a] : rv.x;
                win[a][0] = (w0 > 0)      ? le : 0.f;
                win[a][1] = mv.x; win[a][2] = mv.y;
                win[a][3] = mv.z; win[a][4] = mv.w;
                win[a][5] = (w0 + 4 < IW) ? re : 0.f;
            }
            v4f yy;
#pragma unroll
            for (int j = 0; j < 4; ++j) {
                float acc = 0.f;
#pragma unroll
                for (int a = 0; a < 3; ++a)
#pragma unroll
                    for (int d = 0; d < 3; ++d)
                        acc = fmaf(Kv[j][a * 3 + d], win[a][j + d], acc);
                yy[j] = acc;
            }
            yacc[b] = yy;
        }
        if (b + 1 < NB2) {
            // counted drain: retire stage(b+1) (LDS write landed); keep
            // halo(b+1) x 6 in flight. Then raw barrier (no vmcnt(0) drain).
            VMWAIT(6);
            SCHEDB();
            __builtin_amdgcn_s_barrier();
            SCHEDB();
        }
    }

    // ---- epilogue: fire-and-forget store burst (kernel-end drain) ----
    float* obp = out + (size_t)h * IW + w0;
#pragma unroll
    for (int b = 0; b < NB2; ++b)
        __builtin_nontemporal_store(yacc[b],
                                    (v4f*)(obp + (size_t)(b0 + b) * plane));
}

extern "C" void kernel_launch(void* const* d_in, const int* in_sizes, int n_in,
                              void* d_out, int out_size, void* d_ws, size_t ws_size,
                              hipStream_t stream) {
    const float* image = (const float*)d_in[0]; // 1*1024*1024
    const float* x     = (const float*)d_in[1]; // 16*1*1024*1024
    const float* Wk    = (const float*)d_in[2]; // 9*1*3*3
    const float* bk    = (const float*)d_in[3]; // 9
    float* out = (float*)d_out;                 // 16*1024*1024 f32

    dim3 block(64, 4);
    dim3 grid(4096);                            // 4 batch-groups x 1024 tiles
    fused_ro4<<<grid, block, 0, stream>>>(image, x, Wk, bk, out);
}

// Round 11
// 125.414 us; speedup vs baseline: 2.7149x; 1.6533x over previous
//
#include <hip/hip_runtime.h>

// image (1,1024,1024) f32, x (16,1,1024,1024) f32, W_KL (9,1,3,3) f32, b_KL (9,) f32.
// y[b,h,w] = sum_{a,d} (conv(image,W_KL)[a*3+d][h,w] + b[a*3+d]) * x[b,h+a-1,w+d-1]
#define IH 1024
#define IW 1024
#define NB 16

typedef float v4f __attribute__((ext_vector_type(4)));

#define VMWAIT(n) asm volatile("s_waitcnt vmcnt(" #n ")" ::: "memory")
#define SCHEDB()  __builtin_amdgcn_sched_barrier(0)

__device__ __forceinline__ void glds16(const float* g, float* l) {
    __builtin_amdgcn_global_load_lds(
        (const __attribute__((address_space(1))) void*)g,
        (__attribute__((address_space(3))) void*)l, 16, 0, 0);
}

// Image window in registers: aligned v4f core + scalar halo dwords, rows
// clamped in-bounds; zero-padding applied in fin_win_img.
struct RawWin { v4f mv[3]; float fl[3]; float fr[3]; };

__device__ __forceinline__ void issue_win(const float* __restrict__ plane,
                                          int h, int w0, RawWin& rw) {
#pragma unroll
    for (int a = 0; a < 3; ++a) {
        const int hh = h + a - 1;
        const int hc = (hh < 0) ? 0 : (hh >= IH ? IH - 1 : hh);
        const float* rowp = plane + (size_t)hc * IW;
        rw.fl[a] = rowp[w0 > 0 ? w0 - 1 : 0];
        rw.mv[a] = *(const v4f*)(rowp + w0);
        rw.fr[a] = rowp[w0 + 4 < IW ? w0 + 4 : IW - 1];
    }
}

__device__ __forceinline__ void fin_win_img(const RawWin& rw, int h, int w0,
                                            float win[3][6]) {
#pragma unroll
    for (int a = 0; a < 3; ++a) {
        const int hh = h + a - 1;
        const bool rowok = (hh >= 0) & (hh < IH);
        win[a][0] = (rowok && w0 > 0)      ? rw.fl[a]   : 0.f;
        win[a][1] = rowok ? rw.mv[a].x : 0.f;
        win[a][2] = rowok ? rw.mv[a].y : 0.f;
        win[a][3] = rowok ? rw.mv[a].z : 0.f;
        win[a][4] = rowok ? rw.mv[a].w : 0.f;
        win[a][5] = (rowok && w0 + 4 < IW) ? rw.fr[a]   : 0.f;
    }
}

// EXACT round-4 kernel (best measured: bench 123.9, clean compile) with one
// zero-register-cost change: the per-batch store is issued LAST in the
// per-iter VMEM group instead of FIRST.
//   r4:  [store(b-1), stage xG, halo x6] + VMWAIT(6)
//        -> in-order vmcnt retirement forced the nt store (HBM-deep ack)
//           to fully retire EVERY iteration with ZERO issue-to-wait slack,
//           phase-locked across all waves at the barrier. This is why the
//           MLP/occupancy/depth levers (r5/r7/r8) were all null.
//   now: [stage xG, halo x6, store(b-1)] + VMWAIT(7)
//        -> W_b retires stage(b+1) (+store(b-2), issued TWO iters ago);
//           store(b-1) stays in flight as the youngest op. Each store gets
//           ~2 compute phases + a barrier of ack slack instead of 0.
// r9/r10 lesson honored: live set is byte-identical to r4 (yprev only) —
// no yacc array, no extra buffering, nothing for the spiller to eat.
__global__ __launch_bounds__(256, 4) void fused_stlast(
    const float* __restrict__ image,
    const float* __restrict__ x,
    const float* __restrict__ Wk,
    const float* __restrict__ bk,
    float* __restrict__ out)
{
    __shared__ float lds[2][6][256];          // 12 KiB -> 4 blocks/CU fits

    const int tx = threadIdx.x;               // lane 0..63
    const int wv = threadIdx.y;               // wave 0..3 = row within group

    // XCD-band swizzle (r4-verified): xcd = hwid%8 owns a contiguous band
    // of 128 rows, so blocks sharing staging rows hit the same L2.
    const int hwid  = blockIdx.x;             // 0..1023
    const int xcd   = hwid & 7;
    const int chunk = hwid >> 3;              // 0..127
    const int bx    = chunk & 3;              // col-tile 0..3
    const int g     = xcd * 32 + (chunk >> 2);// row-group 0..255 (bijective)
    const int c0    = bx * 256;
    const int h0    = g * 4;
    const int h     = h0 + wv;
    const int lc    = tx * 4;                 // local col of first out px
    const int w0    = c0 + lc;                // global col

    const size_t plane = (size_t)IH * IW;

    // Opaque zero in a VGPR: forces halo broadcast loads to stay VMEM
    // (scalarization to SMEM would silently break the vmcnt group counts).
    int zv; asm("v_mov_b32 %0, 0" : "=v"(zv));

    // stage batch b's 6-row tile into lds[buf]: wave wv does row wv
    // (+ row wv+4 for wv<2): G = 2,2,1,1 glds per wave.
    auto stage = [&](int b, int buf) {
        const float* xb = x + (size_t)b * plane;
        int gr = h0 - 1 + wv; gr = gr < 0 ? 0 : gr;               // rows -1..2 clamp lo
        glds16(xb + (size_t)gr * IW + c0 + tx * 4, &lds[buf][wv][0]);
        if (wv < 2) {
            int g2 = h0 + 3 + wv; g2 = g2 > IH - 1 ? IH - 1 : g2; // rows 3..4 clamp hi
            glds16(xb + (size_t)g2 * IW + c0 + tx * 4, &lds[buf][wv + 4][0]);
        }
    };
    // column-halo for batch b: cols c0-1 / c0+256 for this thread's 3 rows,
    // broadcast loads (all lanes same address), 6 VMEM ops per wave.
    auto halo = [&](int b, float* HL, float* HR) {
        const float* xb = x + (size_t)b * plane;
        const int cl = (c0 > 0) ? c0 - 1 : 0;
        const int cr = (c0 + 256 < IW) ? c0 + 256 : IW - 1;
#pragma unroll
        for (int a = 0; a < 3; ++a) {
            int gr = h + a - 1; gr = gr < 0 ? 0 : (gr > IH - 1 ? IH - 1 : gr);
            const float* rp = xb + (size_t)gr * IW;
            HL[a] = rp[cl + zv];
            HR[a] = rp[cr + zv];
        }
    };

    // ---- issue order: image (oldest), stage(0), halo(0) ----
    RawWin rimg;
    issue_win(image, h, w0, rimg);
    stage(0, 0);
    float hl[2][3], hr[2][3];
    halo(0, hl[0], hr[0]);

    // conv weights / bias: uniform addresses -> scalar loads (lgkmcnt, does
    // not perturb the vmcnt counting).
    float wkk[81];
#pragma unroll
    for (int i = 0; i < 81; ++i) wkk[i] = Wk[i];
    float bb[9];
#pragma unroll
    for (int c = 0; c < 9; ++c) bb[c] = bk[c];

    // ---- K phase (auto-wait retires image loads; stage(0) keeps flying) ----
    float p[3][6];
    fin_win_img(rimg, h, w0, p);
    float Kv[4][9];
#pragma unroll
    for (int j = 0; j < 4; ++j)
#pragma unroll
        for (int c = 0; c < 9; ++c) {
            float acc = bb[c];
#pragma unroll
            for (int a = 0; a < 3; ++a)
#pragma unroll
                for (int d = 0; d < 3; ++d)
                    acc = fmaf(wkk[c * 9 + a * 3 + d], p[a][j + d], acc);
            Kv[j][c] = acc;
        }
    // Row-pad masking folded into Kv (staged clamp-row garbage then adds 0).
    {
        const bool top = (h == 0);
        const bool bot = (h == IH - 1);
#pragma unroll
        for (int j = 0; j < 4; ++j)
#pragma unroll
            for (int d = 0; d < 3; ++d) {
                Kv[j][d]     = top ? 0.f : Kv[j][d];
                Kv[j][6 + d] = bot ? 0.f : Kv[j][6 + d];
            }
    }

    // prologue sync: queue = [stage(0) x G, halo(0) x 6] -> vmcnt(6)
    // retires exactly stage(0); halos stay in flight.
    VMWAIT(6);
    SCHEDB();
    __builtin_amdgcn_s_barrier();
    SCHEDB();

    v4f yprev;
    float* obp = out + (size_t)h * IW + w0;
    const int ll = (tx > 0)  ? lc - 4 : 0;    // aligned left-halo b128
    const int lr = (tx < 63) ? lc + 4 : 252;  // aligned right-halo b128

#pragma unroll
    for (int b = 0; b < NB; ++b) {
        // per-iter VMEM group: [stage(b+1) x G, halo(b+1) x 6, store(b-1)]
        // — store LAST (youngest), so no wait ever forces it until two
        // iterations later (W_{b+1} retires it together with stage(b+2)).
        if (b + 1 < NB) {
            stage(b + 1, (b + 1) & 1);                       SCHEDB();
            halo(b + 1, hl[(b + 1) & 1], hr[(b + 1) & 1]);   SCHEDB();
        }
        if (b > 0) {
            __builtin_nontemporal_store(yprev,
                                        (v4f*)(obp + (size_t)(b - 1) * plane));
            SCHEDB();
        }
        // ---- consume batch b from lds[b&1] (auto-wait retires halo(b),
        //      which is OLDER than this iter's group — store untouched) ----
        {
            const float* lb = &lds[b & 1][0][0];
            float win[3][6];
#pragma unroll
            for (int a = 0; a < 3; ++a) {
                const float* rowp = lb + (wv + a) * 256;
                const v4f lv = *(const v4f*)(rowp + ll);
                const v4f mv = *(const v4f*)(rowp + lc);
                const v4f rv = *(const v4f*)(rowp + lr);
                const float le = (tx == 0)  ? hl[b & 1][a] : lv.w;
                const float re = (tx == 63) ? hr[b & 1][a] : rv.x;
                win[a][0] = (w0 > 0)      ? le : 0.f;
                win[a][1] = mv.x; win[a][2] = mv.y;
                win[a][3] = mv.z; win[a][4] = mv.w;
                win[a][5] = (w0 + 4 < IW) ? re : 0.f;
            }
            v4f yy;
#pragma unroll
            for (int j = 0; j < 4; ++j) {
                float acc = 0.f;
#pragma unroll
                for (int a = 0; a < 3; ++a)
#pragma unroll
                    for (int d = 0; d < 3; ++d)
                        acc = fmaf(Kv[j][a * 3 + d], win[a][j + d], acc);
                yy[j] = acc;
            }
            yprev = yy;
        }
        if (b + 1 < NB) {
            // counted drain: b=0 queue is [halo(1) 6] after stage(1) ->
            // vmcnt(6); b>=1 queue is [stage(b+1) G | halo(b+1) 6,
            // store(b-1) 1] -> retire stage, keep 7 -> vmcnt(7).
            if (b == 0) { VMWAIT(6); } else { VMWAIT(7); }
            SCHEDB();
            __builtin_amdgcn_s_barrier();
            SCHEDB();
        }
    }
    __builtin_nontemporal_store(yprev,
                                (v4f*)(obp + (size_t)(NB - 1) * plane));
}

extern "C" void kernel_launch(void* const* d_in, const int* in_sizes, int n_in,
                              void* d_out, int out_size, void* d_ws, size_t ws_size,
                              hipStream_t stream) {
    const float* image = (const float*)d_in[0]; // 1*1024*1024
    const float* x     = (const float*)d_in[1]; // 16*1*1024*1024
    const float* Wk    = (const float*)d_in[2]; // 9*1*3*3
    const float* bk    = (const float*)d_in[3]; // 9
    float* out = (float*)d_out;                 // 16*1024*1024 f32

    dim3 block(64, 4);
    dim3 grid(1024);                            // 4 blocks/CU, uniform work
    fused_stlast<<<grid, block, 0, stream>>>(image, x, Wk, bk, out);
}